// Round 2
// baseline (713.696 us; speedup 1.0000x reference)
//
#include <hip/hip_runtime.h>
#include <cstdint>

#define IN_DIM 128

__device__ __forceinline__ float leaky02(float x) { return x >= 0.f ? x : 0.2f * x; }
__device__ __forceinline__ float elu1(float x) { return x > 0.f ? x : expm1f(x); }

// ---------------- GEMM: C[M,256] = A[M,K] * B[K,256], f32 vector ALU ----------------
template<int K>
__global__ __launch_bounds__(256) void gemm_f32(const float* __restrict__ A,
                                                const float* __restrict__ B,
                                                float* __restrict__ C, int M) {
  constexpr int BM = 128, BN = 128, BK = 16;
  __shared__ float As[BK][BM + 4];  // A stored transposed: As[k][m]
  __shared__ float Bs[BK][BN + 4];
  const int tid = threadIdx.x;
  const int tx = tid & 15, ty = tid >> 4;
  const int row0 = blockIdx.x * BM, col0 = blockIdx.y * BN;

  float acc[8][8];
#pragma unroll
  for (int i = 0; i < 8; ++i)
#pragma unroll
    for (int j = 0; j < 8; ++j) acc[i][j] = 0.f;

  for (int k0 = 0; k0 < K; k0 += BK) {
    // A tile: 128 rows x 16 k = 512 float4, 2 per thread
#pragma unroll
    for (int i = 0; i < 2; ++i) {
      int f = tid + i * 256;
      int r = f >> 2;
      int kq = (f & 3) << 2;
      int row = row0 + r;
      if (row >= M) row = M - 1;  // clamp: value unused (store guarded)
      float4 v = *(const float4*)(A + (size_t)row * K + k0 + kq);
      As[kq + 0][r] = v.x; As[kq + 1][r] = v.y; As[kq + 2][r] = v.z; As[kq + 3][r] = v.w;
    }
    // B tile: 16 k x 128 cols = 512 float4
#pragma unroll
    for (int i = 0; i < 2; ++i) {
      int f = tid + i * 256;
      int kr = f >> 5;
      int c = (f & 31) << 2;
      *(float4*)&Bs[kr][c] = *(const float4*)(B + (size_t)(k0 + kr) * 256 + col0 + c);
    }
    __syncthreads();
#pragma unroll
    for (int kk = 0; kk < BK; ++kk) {
      float a[8], b[8];
      *(float4*)&a[0] = *(const float4*)&As[kk][ty * 8];
      *(float4*)&a[4] = *(const float4*)&As[kk][ty * 8 + 4];
      *(float4*)&b[0] = *(const float4*)&Bs[kk][tx * 8];
      *(float4*)&b[4] = *(const float4*)&Bs[kk][tx * 8 + 4];
#pragma unroll
      for (int i = 0; i < 8; ++i)
#pragma unroll
        for (int j = 0; j < 8; ++j) acc[i][j] = fmaf(a[i], b[j], acc[i][j]);
    }
    __syncthreads();
  }
#pragma unroll
  for (int i = 0; i < 8; ++i) {
    int row = row0 + ty * 8 + i;
    if (row < M) {
      float4 v0 = make_float4(acc[i][0], acc[i][1], acc[i][2], acc[i][3]);
      float4 v1 = make_float4(acc[i][4], acc[i][5], acc[i][6], acc[i][7]);
      *(float4*)(C + (size_t)row * 256 + col0 + tx * 8) = v0;
      *(float4*)(C + (size_t)row * 256 + col0 + tx * 8 + 4) = v1;
    }
  }
}

// ---------------- alpha_s/alpha_d: [N,4] head dots ----------------
// h row layout [4 heads][64 dims]; wave w of the block reduces head w.
__global__ __launch_bounds__(256) void alpha_kernel(const float* __restrict__ h,
                                                    const float* __restrict__ a_src,
                                                    const float* __restrict__ a_dst,
                                                    float* __restrict__ as,
                                                    float* __restrict__ ad, int n) {
  int t = threadIdx.x;
  int lane = t & 63, w = t >> 6;
  float asw = a_src[t], adw = a_dst[t];
  for (int node = blockIdx.x; node < n; node += gridDim.x) {
    float p = h[(size_t)node * 256 + t];
    float vs = p * asw, vd = p * adw;
#pragma unroll
    for (int o = 32; o; o >>= 1) { vs += __shfl_down(vs, o); vd += __shfl_down(vd, o); }
    if (lane == 0) { as[node * 4 + w] = vs; ad[node * 4 + w] = vd; }
  }
}

// ---------------- CSR build: histogram / scan / scatter ----------------
__global__ void hist_kernel(const int* __restrict__ dst, int* __restrict__ counts, int E) {
  for (int e = blockIdx.x * blockDim.x + threadIdx.x; e < E; e += gridDim.x * blockDim.x)
    atomicAdd(&counts[dst[e]], 1);
}

// single block, 1024 threads: exclusive scan of data[0..n) -> offs[0..n], data becomes offsets (cursor)
__global__ __launch_bounds__(1024) void scan_kernel(int* __restrict__ data, int* __restrict__ offs, int n) {
  __shared__ int wsum[16];
  int tid = threadIdx.x;
  int lane = tid & 63, w = tid >> 6;
  int carry = 0;
  for (int base = 0; base < n; base += 1024) {
    int i = base + tid;
    int c = (i < n) ? data[i] : 0;
    int v = c;
#pragma unroll
    for (int o = 1; o < 64; o <<= 1) { int u = __shfl_up(v, o); if (lane >= o) v += u; }
    if (lane == 63) wsum[w] = v;
    __syncthreads();
    if (w == 0 && lane < 16) {
      int s = wsum[lane];
#pragma unroll
      for (int o = 1; o < 16; o <<= 1) { int u = __shfl_up(s, o); if (lane >= o) s += u; }
      wsum[lane] = s;
    }
    __syncthreads();
    int excl = carry + (w ? wsum[w - 1] : 0) + (v - c);
    if (i < n) { offs[i] = excl; data[i] = excl; }
    carry += wsum[15];
    __syncthreads();
  }
  if (tid == 0) offs[n] = carry;
}

__global__ void scatter_kernel(const int* __restrict__ src, const int* __restrict__ dst,
                               int* __restrict__ cursor, int* __restrict__ ssrc, int E) {
  for (int e = blockIdx.x * blockDim.x + threadIdx.x; e < E; e += gridDim.x * blockDim.x) {
    int pos = atomicAdd(&cursor[dst[e]], 1);
    ssrc[pos] = src[e];
  }
}

// ---------------- GAT aggregation: one wave per destination node ----------------
// Fused segment softmax: one gather pass computes logits (register-cached for the
// first 64-edge chunk), butterfly max, exp+sum from registers (re-gather only for
// deg>=64 tail), then weighted gather-accumulate where lanes own the 256 dims.
// Self-loop (src=node) appended implicitly as edge index i==deg.
template<bool MEAN>
__global__ __launch_bounds__(256) void agg_kernel(const float* __restrict__ h,
                                                  const float* __restrict__ as,
                                                  const float* __restrict__ ad,
                                                  const int* __restrict__ offs,
                                                  const int* __restrict__ ssrc,
                                                  const float* __restrict__ bias,
                                                  float* __restrict__ out, int n) {
  int node = blockIdx.x * 4 + (threadIdx.x >> 6);
  if (node >= n) return;
  int lane = threadIdx.x & 63;
  int beg = offs[node];
  int deg = offs[node + 1] - beg;

  float adn[4];
  { float4 t = *(const float4*)&ad[node * 4]; adn[0] = t.x; adn[1] = t.y; adn[2] = t.z; adn[3] = t.w; }

  // ---- phase 1: logits + max over incoming edges (incl. self) per head.
  // First-chunk logits (i == lane) cached in registers.
  float lg[4];
  float m[4] = {-1e30f, -1e30f, -1e30f, -1e30f};
  for (int i = lane; i <= deg; i += 64) {
    int s = (i < deg) ? ssrc[beg + i] : node;
    float4 a4 = *(const float4*)&as[s * 4];
    float l0 = leaky02(a4.x + adn[0]);
    float l1 = leaky02(a4.y + adn[1]);
    float l2 = leaky02(a4.z + adn[2]);
    float l3 = leaky02(a4.w + adn[3]);
    if (i == lane) { lg[0] = l0; lg[1] = l1; lg[2] = l2; lg[3] = l3; }
    m[0] = fmaxf(m[0], l0); m[1] = fmaxf(m[1], l1);
    m[2] = fmaxf(m[2], l2); m[3] = fmaxf(m[3], l3);
  }
#pragma unroll
  for (int o = 32; o; o >>= 1)
#pragma unroll
    for (int hh = 0; hh < 4; ++hh) m[hh] = fmaxf(m[hh], __shfl_xor(m[hh], o));

  // ---- phase 2: sum of exp (register-cached first chunk; re-gather only deg>=64 tail)
  float sm[4] = {0.f, 0.f, 0.f, 0.f};
  if (lane <= deg) {
#pragma unroll
    for (int hh = 0; hh < 4; ++hh) sm[hh] = __expf(lg[hh] - m[hh]);
  }
  for (int i = lane + 64; i <= deg; i += 64) {
    int s = (i < deg) ? ssrc[beg + i] : node;
    float4 a4 = *(const float4*)&as[s * 4];
    sm[0] += __expf(leaky02(a4.x + adn[0]) - m[0]);
    sm[1] += __expf(leaky02(a4.y + adn[1]) - m[1]);
    sm[2] += __expf(leaky02(a4.z + adn[2]) - m[2]);
    sm[3] += __expf(leaky02(a4.w + adn[3]) - m[3]);
  }
#pragma unroll
  for (int o = 32; o; o >>= 1)
#pragma unroll
    for (int hh = 0; hh < 4; ++hh) sm[hh] += __shfl_xor(sm[hh], o);

  float inv[4];
#pragma unroll
  for (int hh = 0; hh < 4; ++hh) inv[hh] = 1.f / (sm[hh] + 1e-16f);

  // ---- phase 3: weighted accumulate; lane owns dims [lane*4, lane*4+4), head = lane/16
  int hsel = lane >> 4;
  float mh = m[hsel], invh = inv[hsel], adh = adn[hsel];
  float ax = 0.f, ay = 0.f, az = 0.f, aw = 0.f;
  for (int i = 0; i <= deg; ++i) {
    int s = (i < deg) ? ssrc[beg + i] : node;
    float w = __expf(leaky02(as[s * 4 + hsel] + adh) - mh) * invh;
    float4 hv = *(const float4*)&h[(size_t)s * 256 + lane * 4];
    ax = fmaf(hv.x, w, ax); ay = fmaf(hv.y, w, ay);
    az = fmaf(hv.z, w, az); aw = fmaf(hv.w, w, aw);
  }

  if (!MEAN) {
    float4 b = *(const float4*)&bias[lane * 4];
    float4 o;
    o.x = elu1(ax + b.x); o.y = elu1(ay + b.y);
    o.z = elu1(az + b.z); o.w = elu1(aw + b.w);
    *(float4*)&out[(size_t)node * 256 + lane * 4] = o;  // ELU fused (feeds layer 2)
  } else {
    // mean over 4 heads: lanes {l, l+16, l+32, l+48} hold same dim, different head
#pragma unroll
    for (int o = 16; o <= 32; o <<= 1) {
      ax += __shfl_xor(ax, o); ay += __shfl_xor(ay, o);
      az += __shfl_xor(az, o); aw += __shfl_xor(aw, o);
    }
    if (lane < 16) {
      float4 b = *(const float4*)&bias[lane * 4];
      float4 o;
      o.x = ax * 0.25f + b.x; o.y = ay * 0.25f + b.y;
      o.z = az * 0.25f + b.z; o.w = aw * 0.25f + b.w;
      *(float4*)&out[(size_t)node * 64 + lane * 4] = o;
    }
  }
}

extern "C" void kernel_launch(void* const* d_in, const int* in_sizes, int n_in,
                              void* d_out, int out_size, void* d_ws, size_t ws_size,
                              hipStream_t stream) {
  const float* x    = (const float*)d_in[0];
  const int*   ei   = (const int*)d_in[1];
  const float* W1   = (const float*)d_in[2];
  const float* a_s1 = (const float*)d_in[3];
  const float* a_d1 = (const float*)d_in[4];
  const float* b1   = (const float*)d_in[5];
  const float* W2   = (const float*)d_in[6];
  const float* a_s2 = (const float*)d_in[7];
  const float* a_d2 = (const float*)d_in[8];
  const float* b2   = (const float*)d_in[9];
  float* out = (float*)d_out;

  const int N = in_sizes[0] / IN_DIM;
  const int E = in_sizes[1] / 2;
  const int* esrc = ei;
  const int* edst = ei + E;

  char* p = (char*)d_ws;
  auto alloc = [&](size_t bytes) { char* r = p; p += (bytes + 255) & ~(size_t)255; return r; };
  float* h1   = (float*)alloc((size_t)N * 256 * 4);
  float* hb   = (float*)alloc((size_t)N * 256 * 4);
  float* as1  = (float*)alloc((size_t)N * 4 * 4);
  float* ad1  = (float*)alloc((size_t)N * 4 * 4);
  float* as2  = (float*)alloc((size_t)N * 4 * 4);
  float* ad2  = (float*)alloc((size_t)N * 4 * 4);
  int* offs   = (int*)alloc((size_t)(N + 1) * 4);
  int* cursor = (int*)alloc((size_t)N * 4);
  int* ssrc   = (int*)alloc((size_t)E * 4);
  float* g = h1;  // GEMM2 output reuses h1 (dead after agg layer 1)

  // counts must start at 0 (ws is poisoned with 0xAA before every call)
  hipMemsetAsync(cursor, 0, (size_t)N * 4, stream);

  // ---- CSR build (shared by both layers)
  hist_kernel<<<1024, 256, 0, stream>>>(edst, cursor, E);
  scan_kernel<<<1, 1024, 0, stream>>>(cursor, offs, N);
  scatter_kernel<<<1024, 256, 0, stream>>>(esrc, edst, cursor, ssrc, E);

  // ---- layer 1
  dim3 gg1((N + 127) / 128, 2);
  gemm_f32<128><<<gg1, 256, 0, stream>>>(x, W1, h1, N);
  alpha_kernel<<<2048, 256, 0, stream>>>(h1, a_s1, a_d1, as1, ad1, N);
  agg_kernel<false><<<(N + 3) / 4, 256, 0, stream>>>(h1, as1, ad1, offs, ssrc, b1, hb, N);

  // ---- layer 2
  dim3 gg2((N + 127) / 128, 2);
  gemm_f32<256><<<gg2, 256, 0, stream>>>(hb, W2, g, N);
  alpha_kernel<<<2048, 256, 0, stream>>>(g, a_s2, a_d2, as2, ad2, N);
  agg_kernel<true><<<(N + 3) / 4, 256, 0, stream>>>(g, as2, ad2, offs, ssrc, b2, out, N);
}

// Round 6
// 505.409 us; speedup vs baseline: 1.4121x; 1.4121x over previous
//
#include <hip/hip_runtime.h>
#include <hip/hip_fp16.h>
#include <cstdint>

#define IN_DIM 128

__device__ __forceinline__ float leaky02(float x) { return x >= 0.f ? x : 0.2f * x; }
__device__ __forceinline__ float elu1(float x) { return x > 0.f ? x : expm1f(x); }
__device__ __forceinline__ float h2f(unsigned short u) {
  __half_raw r; r.x = u;
  return __half2float(__half(r));
}
__device__ __forceinline__ unsigned short f2h(float f) {  // RNE
  __half h = __float2half_rn(f);
  return __half_as_ushort(h);
}

// ---------------- fused GEMM: h16 = fp16(A@B), as/ad = per-head dots ----------------
// C[M,256] = A[M,K] @ B[K,256] on the f32 vector ALU (no f32 MFMA on CDNA4).
// Block covers 128 rows x 128 cols = 2 heads; epilogue reduces a_src/a_dst dots
// per row via 8-lane shfl_xor and stores h only as fp16 (the only consumer format;
// fp16 over bf16: 8x lower rounding error, same bytes).
template<int K>
__global__ __launch_bounds__(256) void gemm_fused(const float* __restrict__ A,
                                                  const float* __restrict__ B,
                                                  const float* __restrict__ a_srcv,
                                                  const float* __restrict__ a_dstv,
                                                  unsigned short* __restrict__ h16,
                                                  float* __restrict__ as,
                                                  float* __restrict__ ad, int M) {
  constexpr int BM = 128, BN = 128, BK = 16;
  __shared__ float As[BK][BM + 4];  // A transposed: As[k][m]
  __shared__ float Bs[BK][BN + 4];
  const int tid = threadIdx.x;
  const int tx = tid & 15, ty = tid >> 4;
  const int row0 = blockIdx.x * BM, col0 = blockIdx.y * BN;

  // attention vectors for this thread's 8 columns (flat layout [H*64] == col index)
  float asv[8], adv[8];
#pragma unroll
  for (int j = 0; j < 8; ++j) {
    asv[j] = a_srcv[col0 + tx * 8 + j];
    adv[j] = a_dstv[col0 + tx * 8 + j];
  }

  float acc[8][8];
#pragma unroll
  for (int i = 0; i < 8; ++i)
#pragma unroll
    for (int j = 0; j < 8; ++j) acc[i][j] = 0.f;

  for (int k0 = 0; k0 < K; k0 += BK) {
#pragma unroll
    for (int i = 0; i < 2; ++i) {
      int f = tid + i * 256;
      int r = f >> 2;
      int kq = (f & 3) << 2;
      int row = row0 + r;
      if (row >= M) row = M - 1;  // clamp: result discarded (stores guarded)
      float4 v = *(const float4*)(A + (size_t)row * K + k0 + kq);
      As[kq + 0][r] = v.x; As[kq + 1][r] = v.y; As[kq + 2][r] = v.z; As[kq + 3][r] = v.w;
    }
#pragma unroll
    for (int i = 0; i < 2; ++i) {
      int f = tid + i * 256;
      int kr = f >> 5;
      int c = (f & 31) << 2;
      *(float4*)&Bs[kr][c] = *(const float4*)(B + (size_t)(k0 + kr) * 256 + col0 + c);
    }
    __syncthreads();
#pragma unroll
    for (int kk = 0; kk < BK; ++kk) {
      float a[8], b[8];
      *(float4*)&a[0] = *(const float4*)&As[kk][ty * 8];
      *(float4*)&a[4] = *(const float4*)&As[kk][ty * 8 + 4];
      *(float4*)&b[0] = *(const float4*)&Bs[kk][tx * 8];
      *(float4*)&b[4] = *(const float4*)&Bs[kk][tx * 8 + 4];
#pragma unroll
      for (int i = 0; i < 8; ++i)
#pragma unroll
        for (int j = 0; j < 8; ++j) acc[i][j] = fmaf(a[i], b[j], acc[i][j]);
    }
    __syncthreads();
  }

  // epilogue: per-row head dots + fp16 store
#pragma unroll
  for (int i = 0; i < 8; ++i) {
    int row = row0 + ty * 8 + i;
    float ds = 0.f, dd = 0.f;
#pragma unroll
    for (int j = 0; j < 8; ++j) {
      ds = fmaf(acc[i][j], asv[j], ds);
      dd = fmaf(acc[i][j], adv[j], dd);
    }
    // reduce across the 8 lanes of this head (tx 0-7 -> head0, tx 8-15 -> head1)
#pragma unroll
    for (int mk = 1; mk < 8; mk <<= 1) {
      ds += __shfl_xor(ds, mk);
      dd += __shfl_xor(dd, mk);
    }
    if (row < M) {
      if ((tx & 7) == 0) {
        int head = (col0 >> 6) + (tx >> 3);
        as[row * 4 + head] = ds;
        ad[row * 4 + head] = dd;
      }
      uint4 pk;
      pk.x = (unsigned)f2h(acc[i][0]) | ((unsigned)f2h(acc[i][1]) << 16);
      pk.y = (unsigned)f2h(acc[i][2]) | ((unsigned)f2h(acc[i][3]) << 16);
      pk.z = (unsigned)f2h(acc[i][4]) | ((unsigned)f2h(acc[i][5]) << 16);
      pk.w = (unsigned)f2h(acc[i][6]) | ((unsigned)f2h(acc[i][7]) << 16);
      *(uint4*)&h16[(size_t)row * 256 + col0 + tx * 8] = pk;
    }
  }
}

// ---------------- CSR build: histogram / 3-kernel scan / scatter ----------------
__global__ void hist_kernel(const int* __restrict__ dst, int* __restrict__ counts, int E) {
  for (int e = blockIdx.x * blockDim.x + threadIdx.x; e < E; e += gridDim.x * blockDim.x)
    atomicAdd(&counts[dst[e]], 1);
}

// A: per-1024-chunk sums
__global__ __launch_bounds__(256) void scanA(const int* __restrict__ counts,
                                             int* __restrict__ partials, int n) {
  __shared__ int wsum[4];
  int tid = threadIdx.x, lane = tid & 63, w = tid >> 6;
  int i0 = blockIdx.x * 1024 + tid * 4;
  int s = 0;
#pragma unroll
  for (int j = 0; j < 4; ++j) { int i = i0 + j; if (i < n) s += counts[i]; }
#pragma unroll
  for (int o = 32; o; o >>= 1) s += __shfl_xor(s, o);
  if (lane == 0) wsum[w] = s;
  __syncthreads();
  if (tid == 0) partials[blockIdx.x] = wsum[0] + wsum[1] + wsum[2] + wsum[3];
}

// B: exclusive scan of chunk partials (single wave, generic carry loop) + total
__global__ __launch_bounds__(64) void scanB(int* __restrict__ partials, int nchunks,
                                            int* __restrict__ offs, int n) {
  int lane = threadIdx.x;
  int carry = 0;
  for (int base = 0; base < nchunks; base += 64) {
    int i = base + lane;
    int c = (i < nchunks) ? partials[i] : 0;
    int v = c;
#pragma unroll
    for (int o = 1; o < 64; o <<= 1) { int u = __shfl_up(v, o); if (lane >= o) v += u; }
    if (i < nchunks) partials[i] = carry + v - c;
    carry += __shfl(v, 63);
  }
  if (lane == 0) offs[n] = carry;
}

// C: local exclusive re-scan + chunk base; writes offs and cursor
__global__ __launch_bounds__(256) void scanC(const int* __restrict__ counts,
                                             const int* __restrict__ partials,
                                             int* __restrict__ offs,
                                             int* __restrict__ cursor, int n) {
  __shared__ int wsum[4];
  int tid = threadIdx.x, lane = tid & 63, w = tid >> 6;
  int i0 = blockIdx.x * 1024 + tid * 4;
  int c[4]; int s = 0;
#pragma unroll
  for (int j = 0; j < 4; ++j) { int i = i0 + j; c[j] = (i < n) ? counts[i] : 0; s += c[j]; }
  int v = s;
#pragma unroll
  for (int o = 1; o < 64; o <<= 1) { int u = __shfl_up(v, o); if (lane >= o) v += u; }
  if (lane == 63) wsum[w] = v;
  __syncthreads();
  int wbase = 0;
#pragma unroll
  for (int j = 0; j < 4; ++j) if (j < w) wbase += wsum[j];
  int run = partials[blockIdx.x] + wbase + (v - s);
#pragma unroll
  for (int j = 0; j < 4; ++j) {
    int i = i0 + j;
    if (i < n) { offs[i] = run; cursor[i] = run; run += c[j]; }
  }
}

__global__ void scatter_kernel(const int* __restrict__ src, const int* __restrict__ dst,
                               int* __restrict__ cursor, int* __restrict__ ssrc, int E) {
  for (int e = blockIdx.x * blockDim.x + threadIdx.x; e < E; e += gridDim.x * blockDim.x) {
    int pos = atomicAdd(&cursor[dst[e]], 1);
    ssrc[pos] = src[e];
  }
}

// ---------------- GAT aggregation: one wave per destination node ----------------
// Phases 1+2: fused segment softmax (register-cached first 64-edge chunk).
// Phase 3: fp16 gather of h rows (512B/row); self-loop hoisted out of the loop,
// x2 unroll with dual accumulator sets for FMA ILP (loads remain the limiter).
template<bool MEAN>
__global__ __launch_bounds__(256) void agg_kernel(const unsigned short* __restrict__ h16,
                                                  const float* __restrict__ as,
                                                  const float* __restrict__ ad,
                                                  const int* __restrict__ offs,
                                                  const int* __restrict__ ssrc,
                                                  const float* __restrict__ bias,
                                                  float* __restrict__ out, int n) {
  int node = blockIdx.x * 4 + (threadIdx.x >> 6);
  if (node >= n) return;
  int lane = threadIdx.x & 63;
  int beg = offs[node];
  int deg = offs[node + 1] - beg;

  float adn[4];
  { float4 t = *(const float4*)&ad[node * 4]; adn[0] = t.x; adn[1] = t.y; adn[2] = t.z; adn[3] = t.w; }

  // ---- phase 1: logits + per-head max (self-loop at index deg)
  float lg[4];
  float m[4] = {-1e30f, -1e30f, -1e30f, -1e30f};
  for (int i = lane; i <= deg; i += 64) {
    int s = (i < deg) ? ssrc[beg + i] : node;
    float4 a4 = *(const float4*)&as[s * 4];
    float l0 = leaky02(a4.x + adn[0]);
    float l1 = leaky02(a4.y + adn[1]);
    float l2 = leaky02(a4.z + adn[2]);
    float l3 = leaky02(a4.w + adn[3]);
    if (i == lane) { lg[0] = l0; lg[1] = l1; lg[2] = l2; lg[3] = l3; }
    m[0] = fmaxf(m[0], l0); m[1] = fmaxf(m[1], l1);
    m[2] = fmaxf(m[2], l2); m[3] = fmaxf(m[3], l3);
  }
#pragma unroll
  for (int o = 32; o; o >>= 1)
#pragma unroll
    for (int hh = 0; hh < 4; ++hh) m[hh] = fmaxf(m[hh], __shfl_xor(m[hh], o));

  // ---- phase 2: sum of exp
  float sm[4] = {0.f, 0.f, 0.f, 0.f};
  if (lane <= deg) {
#pragma unroll
    for (int hh = 0; hh < 4; ++hh) sm[hh] = __expf(lg[hh] - m[hh]);
  }
  for (int i = lane + 64; i <= deg; i += 64) {
    int s = (i < deg) ? ssrc[beg + i] : node;
    float4 a4 = *(const float4*)&as[s * 4];
    sm[0] += __expf(leaky02(a4.x + adn[0]) - m[0]);
    sm[1] += __expf(leaky02(a4.y + adn[1]) - m[1]);
    sm[2] += __expf(leaky02(a4.z + adn[2]) - m[2]);
    sm[3] += __expf(leaky02(a4.w + adn[3]) - m[3]);
  }
#pragma unroll
  for (int o = 32; o; o >>= 1)
#pragma unroll
    for (int hh = 0; hh < 4; ++hh) sm[hh] += __shfl_xor(sm[hh], o);

  float inv[4];
#pragma unroll
  for (int hh = 0; hh < 4; ++hh) inv[hh] = 1.f / (sm[hh] + 1e-16f);

  // ---- phase 3: weighted fp16 gather; lane owns dims [lane*4, lane*4+4), head = lane/16
  int hsel = lane >> 4;
  float mh = m[hsel], invh = inv[hsel], adh = adn[hsel];

  // self-loop contribution (hoisted: loop below is pure edge streaming)
  float wS = __expf(leaky02(as[node * 4 + hsel] + adh) - mh) * invh;
  ushort4 uS = *(const ushort4*)&h16[(size_t)node * 256 + lane * 4];
  float ax = h2f(uS.x) * wS, ay = h2f(uS.y) * wS;
  float az = h2f(uS.z) * wS, aw = h2f(uS.w) * wS;
  float bx = 0.f, by = 0.f, bz = 0.f, bw = 0.f;

  int i = 0;
  for (; i + 2 <= deg; i += 2) {
    int s0 = ssrc[beg + i];
    int s1 = ssrc[beg + i + 1];
    float w0 = __expf(leaky02(as[s0 * 4 + hsel] + adh) - mh) * invh;
    float w1 = __expf(leaky02(as[s1 * 4 + hsel] + adh) - mh) * invh;
    ushort4 u0 = *(const ushort4*)&h16[(size_t)s0 * 256 + lane * 4];
    ushort4 u1 = *(const ushort4*)&h16[(size_t)s1 * 256 + lane * 4];
    ax = fmaf(h2f(u0.x), w0, ax); ay = fmaf(h2f(u0.y), w0, ay);
    az = fmaf(h2f(u0.z), w0, az); aw = fmaf(h2f(u0.w), w0, aw);
    bx = fmaf(h2f(u1.x), w1, bx); by = fmaf(h2f(u1.y), w1, by);
    bz = fmaf(h2f(u1.z), w1, bz); bw = fmaf(h2f(u1.w), w1, bw);
  }
  if (i < deg) {
    int s0 = ssrc[beg + i];
    float w0 = __expf(leaky02(as[s0 * 4 + hsel] + adh) - mh) * invh;
    ushort4 u0 = *(const ushort4*)&h16[(size_t)s0 * 256 + lane * 4];
    ax = fmaf(h2f(u0.x), w0, ax); ay = fmaf(h2f(u0.y), w0, ay);
    az = fmaf(h2f(u0.z), w0, az); aw = fmaf(h2f(u0.w), w0, aw);
  }
  ax += bx; ay += by; az += bz; aw += bw;

  if (!MEAN) {
    float4 b = *(const float4*)&bias[lane * 4];
    float4 o;
    o.x = elu1(ax + b.x); o.y = elu1(ay + b.y);
    o.z = elu1(az + b.z); o.w = elu1(aw + b.w);
    *(float4*)&out[(size_t)node * 256 + lane * 4] = o;  // ELU fused (feeds GEMM2)
  } else {
    // mean over 4 heads: lanes {l, l+16, l+32, l+48} hold same dim
#pragma unroll
    for (int o = 16; o <= 32; o <<= 1) {
      ax += __shfl_xor(ax, o); ay += __shfl_xor(ay, o);
      az += __shfl_xor(az, o); aw += __shfl_xor(aw, o);
    }
    if (lane < 16) {
      float4 b = *(const float4*)&bias[lane * 4];
      float4 o;
      o.x = ax * 0.25f + b.x; o.y = ay * 0.25f + b.y;
      o.z = az * 0.25f + b.z; o.w = aw * 0.25f + b.w;
      *(float4*)&out[(size_t)node * 64 + lane * 4] = o;
    }
  }
}

extern "C" void kernel_launch(void* const* d_in, const int* in_sizes, int n_in,
                              void* d_out, int out_size, void* d_ws, size_t ws_size,
                              hipStream_t stream) {
  const float* x    = (const float*)d_in[0];
  const int*   ei   = (const int*)d_in[1];
  const float* W1   = (const float*)d_in[2];
  const float* a_s1 = (const float*)d_in[3];
  const float* a_d1 = (const float*)d_in[4];
  const float* b1   = (const float*)d_in[5];
  const float* W2   = (const float*)d_in[6];
  const float* a_s2 = (const float*)d_in[7];
  const float* a_d2 = (const float*)d_in[8];
  const float* b2   = (const float*)d_in[9];
  float* out = (float*)d_out;

  const int N = in_sizes[0] / IN_DIM;
  const int E = in_sizes[1] / 2;
  const int* esrc = ei;
  const int* edst = ei + E;

  char* p = (char*)d_ws;
  auto alloc = [&](size_t bytes) { char* r = p; p += (bytes + 255) & ~(size_t)255; return r; };
  float* hb            = (float*)alloc((size_t)N * 256 * 4);          // layer-1 output (f32, GEMM2 A)
  unsigned short* h16  = (unsigned short*)alloc((size_t)N * 256 * 2); // fp16 h (layer1) then g (layer2)
  float* as1  = (float*)alloc((size_t)N * 4 * 4);
  float* ad1  = (float*)alloc((size_t)N * 4 * 4);
  float* as2  = (float*)alloc((size_t)N * 4 * 4);
  float* ad2  = (float*)alloc((size_t)N * 4 * 4);
  int* counts  = (int*)alloc((size_t)N * 4);
  int* offs    = (int*)alloc((size_t)(N + 1) * 4);
  int* cursor  = (int*)alloc((size_t)N * 4);
  int* partials= (int*)alloc(4096);
  int* ssrc    = (int*)alloc((size_t)E * 4);

  const int nchunks = (N + 1023) / 1024;

  hipMemsetAsync(counts, 0, (size_t)N * 4, stream);

  // ---- CSR build (shared by both layers)
  hist_kernel<<<1024, 256, 0, stream>>>(edst, counts, E);
  scanA<<<nchunks, 256, 0, stream>>>(counts, partials, N);
  scanB<<<1, 64, 0, stream>>>(partials, nchunks, offs, N);
  scanC<<<nchunks, 256, 0, stream>>>(counts, partials, offs, cursor, N);
  scatter_kernel<<<1024, 256, 0, stream>>>(esrc, edst, cursor, ssrc, E);

  // ---- layer 1 (alpha fused into GEMM epilogue; h stored fp16-only)
  dim3 gg1((N + 127) / 128, 2);
  gemm_fused<128><<<gg1, 256, 0, stream>>>(x, W1, a_s1, a_d1, h16, as1, ad1, N);
  agg_kernel<false><<<(N + 3) / 4, 256, 0, stream>>>(h16, as1, ad1, offs, ssrc, b1, hb, N);

  // ---- layer 2 (g16 reuses h16 buffer: h16 dead after agg1)
  dim3 gg2((N + 127) / 128, 2);
  gemm_fused<256><<<gg2, 256, 0, stream>>>(hb, W2, a_s2, a_d2, h16, as2, ad2, N);
  agg_kernel<true><<<(N + 3) / 4, 256, 0, stream>>>(h16, as2, ad2, offs, ssrc, b2, out, N);
}